// Round 7
// baseline (981.151 us; speedup 1.0000x reference)
//
#include <hip/hip_runtime.h>

// VariationalMPS: <M|H|M> / <M|M> via split-half environment sweeps.
// R7: fused per-site kernel (R6) with fixed parallelism: p-slice 1 -> 288
// blocks (all CUs), 4-deep register prefetch in phase 1, aligned b128 T2
// rows in LDS for phase 3. 23 dispatches total.

#define D 128
#define W 8
#define NS 40
#define HALF 20
#define MSZ 32768   // floats per site M (128*2*128)
#define HSZ 256     // floats per site H
#define LSZ 131072  // energy env (128*8*128)
#define NSZ 16384   // norm env (128*128)

// workspace float offsets (double-buffered envs)
#define OFF_LL0 0
#define OFF_LR0 262144
#define OFF_NL0 524288
#define OFF_NR0 557056
#define OFF_MREV 589824                  // 20*32768
#define OFF_HREV 1245184                 // 20*256
#define OFF_PART 1250304                 // 128 energy partials
#define OFF_PARTN 1250432                // 128 norm partials

// init boundary envs + reversed tensors:
// Mrev[k][p][i][a] = M[39-k][a][i][p];  Hrev[k][x][w][i][j] = H[39-k][w][x][i][j]
__global__ __launch_bounds__(256) void k_prep(const float* __restrict__ Min,
                                              const float* __restrict__ Hin,
                                              float* __restrict__ ws) {
    int gid = blockIdx.x * 256 + threadIdx.x;
    int gsz = gridDim.x * 256;
    for (int i = gid; i < LSZ; i += gsz) {
        ws[OFF_LL0 + i] = (i == 0) ? 1.f : 0.f;               // L_left[0,0,0]
        ws[OFF_LR0 + i] = (i == (W - 1) * D) ? 1.f : 0.f;     // L_right[0,W-1,0]
    }
    for (int i = gid; i < NSZ; i += gsz) {
        ws[OFF_NL0 + i] = (i == 0) ? 1.f : 0.f;
        ws[OFF_NR0 + i] = (i == 0) ? 1.f : 0.f;
    }
    for (int idx = gid; idx < HALF * MSZ; idx += gsz) {
        int k = idx >> 15;
        int r = idx & (MSZ - 1);
        int p = r >> 8, i = (r >> 7) & 1, a = r & 127;
        ws[OFF_MREV + idx] = Min[(NS - 1 - k) * MSZ + a * 256 + i * 128 + p];
    }
    for (int idx = gid; idx < HALF * HSZ; idx += gsz) {
        int k = idx >> 8, r = idx & 255;
        int x = r >> 5, w = (r >> 2) & 7, i = (r >> 1) & 1, j = r & 1;
        ws[OFF_HREV + idx] = Hin[(NS - 1 - k) * HSZ + w * 32 + x * 4 + i * 2 + j];
    }
}

// Fused site-step. Energy blocks 0..255 (128/side, p-slice 1):
//   T1[w,b,i]  = sum_a L[a,w,b] m[a,i,p]   (prefetched float4 L2 loads)
//   T2[j,b,x]  = sum_{w,i} T1 h            (LDS, aligned 12-stride rows)
//   L'[p,x,q]  = sum_{b,j} T2 m[b,j,q]
// Norm blocks 256..287 (16/side, p-slice 8).
__global__ __launch_bounds__(256) void k_step(const float* __restrict__ Min,
                                              const float* __restrict__ Hin,
                                              float* __restrict__ ws, int kk) {
    __shared__ float sm[5696];
    const int bid = blockIdx.x;
    const int t = threadIdx.x;
    const int rd = kk & 1;
    if (bid < 256) {
        const int side = bid >> 7;
        const int p = bid & 127;
        const int baseL = side ? OFF_LR0 : OFF_LL0;
        const float* Lsrc = ws + baseL + rd * LSZ;
        float* Ldst = ws + baseL + (rd ^ 1) * LSZ;
        const float* m = side ? (ws + OFF_MREV + kk * MSZ) : (Min + kk * MSZ);
        const float* h = side ? (ws + OFF_HREV + kk * HSZ) : (Hin + kk * HSZ);
        float* hs = sm;          // [16wi][16xj]
        float* ms = sm + 256;    // [128a][2i]
        float* T1s = sm + 512;   // [16wi][128b pad->132]
        float* T2s = sm + 2624;  // [(j*128+b)*12 + x], rows 16B-aligned
        hs[t] = h[((t >> 4) >> 1) * 32 + ((t & 15) >> 1) * 4 +
                  ((t >> 4) & 1) * 2 + (t & 1)];
        ms[t] = m[(t >> 1) * 256 + (t & 1) * 128 + p]; // [a][i]
        __syncthreads();
        // ---- phase 1: thread owns (w, 4 consecutive b), outputs 4b x 2i ----
        {
            const int w = t >> 5, bq = t & 31;
            float acc[4][2];
#pragma unroll
            for (int u = 0; u < 4; ++u) { acc[u][0] = 0.f; acc[u][1] = 0.f; }
            const float* Lp = Lsrc + w * 128 + bq * 4;
            float4 c0 = *(const float4*)&Lp[0];
            float4 c1 = *(const float4*)&Lp[1024];
            float4 c2 = *(const float4*)&Lp[2048];
            float4 c3 = *(const float4*)&Lp[3072];
#pragma unroll
            for (int g = 0; g < 32; ++g) {
                float4 n0, n1, n2, n3;
                if (g < 31) {
                    const float* Ln = Lp + (g * 4 + 4) * 1024;
                    n0 = *(const float4*)&Ln[0];
                    n1 = *(const float4*)&Ln[1024];
                    n2 = *(const float4*)&Ln[2048];
                    n3 = *(const float4*)&Ln[3072];
                }
                const float4 mv0 = *(const float4*)&ms[g * 8];     // a=4g,4g+1
                const float4 mv1 = *(const float4*)&ms[g * 8 + 4]; // a=4g+2,4g+3
                acc[0][0] += c0.x * mv0.x; acc[0][1] += c0.x * mv0.y;
                acc[1][0] += c0.y * mv0.x; acc[1][1] += c0.y * mv0.y;
                acc[2][0] += c0.z * mv0.x; acc[2][1] += c0.z * mv0.y;
                acc[3][0] += c0.w * mv0.x; acc[3][1] += c0.w * mv0.y;
                acc[0][0] += c1.x * mv0.z; acc[0][1] += c1.x * mv0.w;
                acc[1][0] += c1.y * mv0.z; acc[1][1] += c1.y * mv0.w;
                acc[2][0] += c1.z * mv0.z; acc[2][1] += c1.z * mv0.w;
                acc[3][0] += c1.w * mv0.z; acc[3][1] += c1.w * mv0.w;
                acc[0][0] += c2.x * mv1.x; acc[0][1] += c2.x * mv1.y;
                acc[1][0] += c2.y * mv1.x; acc[1][1] += c2.y * mv1.y;
                acc[2][0] += c2.z * mv1.x; acc[2][1] += c2.z * mv1.y;
                acc[3][0] += c2.w * mv1.x; acc[3][1] += c2.w * mv1.y;
                acc[0][0] += c3.x * mv1.z; acc[0][1] += c3.x * mv1.w;
                acc[1][0] += c3.y * mv1.z; acc[1][1] += c3.y * mv1.w;
                acc[2][0] += c3.z * mv1.z; acc[2][1] += c3.z * mv1.w;
                acc[3][0] += c3.w * mv1.z; acc[3][1] += c3.w * mv1.w;
                c0 = n0; c1 = n1; c2 = n2; c3 = n3;
            }
#pragma unroll
            for (int i = 0; i < 2; ++i) {
                float4 v;
                v.x = acc[0][i]; v.y = acc[1][i]; v.z = acc[2][i]; v.w = acc[3][i];
                *(float4*)&T1s[(w * 2 + i) * 132 + bq * 4] = v;
            }
        }
        __syncthreads();
        // ---- phase 2: thread owns (b, xj-half); h contraction in regs ----
        {
            const int b = t & 127, hh = t >> 7;
            float tv[16];
#pragma unroll
            for (int wi = 0; wi < 16; ++wi) tv[wi] = T1s[wi * 132 + b];
            float o[8];
#pragma unroll
            for (int u = 0; u < 8; ++u) o[u] = 0.f;
#pragma unroll
            for (int wi = 0; wi < 16; ++wi) {
                const float tvv = tv[wi];
                const float4 h0 = *(float4*)&hs[wi * 16 + hh * 8];
                const float4 h1 = *(float4*)&hs[wi * 16 + hh * 8 + 4];
                o[0] += tvv * h0.x; o[1] += tvv * h0.y;
                o[2] += tvv * h0.z; o[3] += tvv * h0.w;
                o[4] += tvv * h1.x; o[5] += tvv * h1.y;
                o[6] += tvv * h1.z; o[7] += tvv * h1.w;
            }
            // o[u] = T2[x = hh*4 + (u>>1)][j = u&1] -> rows [(j*128+b)*12 + x]
            float4 vj0, vj1;
            vj0.x = o[0]; vj0.y = o[2]; vj0.z = o[4]; vj0.w = o[6];
            vj1.x = o[1]; vj1.y = o[3]; vj1.z = o[5]; vj1.w = o[7];
            *(float4*)&T2s[b * 12 + hh * 4] = vj0;
            *(float4*)&T2s[(128 + b) * 12 + hh * 4] = vj1;
        }
        __syncthreads();
        // ---- phase 3: thread owns (q, x-half); K=(b,j)=256 ----
        {
            const int q = t & 127, xh = t >> 7;
            float o3[4] = {0.f, 0.f, 0.f, 0.f};
            const float* mq = m + q;
            float m0 = mq[0], m1 = mq[128];
#pragma unroll 4
            for (int b = 0; b < 128; ++b) {
                float nm0, nm1;
                if (b < 127) { nm0 = mq[(2 * b + 2) * 128]; nm1 = mq[(2 * b + 3) * 128]; }
                const float4 t0 = *(const float4*)&T2s[b * 12 + xh * 4];        // j=0
                const float4 t1 = *(const float4*)&T2s[(128 + b) * 12 + xh * 4]; // j=1
                o3[0] += t0.x * m0; o3[1] += t0.y * m0;
                o3[2] += t0.z * m0; o3[3] += t0.w * m0;
                o3[0] += t1.x * m1; o3[1] += t1.y * m1;
                o3[2] += t1.z * m1; o3[3] += t1.w * m1;
                m0 = nm0; m1 = nm1;
            }
            float* Lo = Ldst + p * 1024 + xh * 512 + q;
#pragma unroll
            for (int x = 0; x < 4; ++x) Lo[x * 128] = o3[x];
        }
    } else {
        // ---- norm block: p-slice of 8 ----
        const int nb = bid - 256;
        const int side = nb >> 4;
        const int p0 = (nb & 15) * 8;
        const int baseN = side ? OFF_NR0 : OFF_NL0;
        const float* Nsrc = ws + baseN + rd * NSZ;
        float* Ndst = ws + baseN + (rd ^ 1) * NSZ;
        const float* m = side ? (ws + OFF_MREV + kk * MSZ) : (Min + kk * MSZ);
        float* msn = sm;        // [128a][i*8+pp]
        float* Tns = sm + 2048; // [256 r=(b,i)][8 p]
#pragma unroll
        for (int u = 0; u < 8; ++u) {
            int e = u * 256 + t;
            int a = e >> 4, i = (e >> 3) & 1, pp = e & 7;
            msn[e] = m[a * 256 + i * 128 + p0 + pp];
        }
        __syncthreads();
        {
            const int b = t >> 1, i = t & 1;
            float acc1[8];
#pragma unroll
            for (int u = 0; u < 8; ++u) acc1[u] = 0.f;
            const float* Np = Nsrc + b;
            const float* mp = msn + i * 8;
            float nv = Np[0];
#pragma unroll 2
            for (int a = 0; a < 128; ++a) {
                float nn;
                if (a < 127) nn = Np[(a + 1) * 128];
                const float4 m0 = *(const float4*)&mp[a * 16];
                const float4 m1 = *(const float4*)&mp[a * 16 + 4];
                acc1[0] += nv * m0.x; acc1[1] += nv * m0.y;
                acc1[2] += nv * m0.z; acc1[3] += nv * m0.w;
                acc1[4] += nv * m1.x; acc1[5] += nv * m1.y;
                acc1[6] += nv * m1.z; acc1[7] += nv * m1.w;
                nv = nn;
            }
            float4 s0, s1;
            s0.x = acc1[0]; s0.y = acc1[1]; s0.z = acc1[2]; s0.w = acc1[3];
            s1.x = acc1[4]; s1.y = acc1[5]; s1.z = acc1[6]; s1.w = acc1[7];
            *(float4*)&Tns[t * 8] = s0;
            *(float4*)&Tns[t * 8 + 4] = s1;
        }
        __syncthreads();
        {
            const int q = t & 127, ph = t >> 7;
            float a3[4] = {0.f, 0.f, 0.f, 0.f};
            const float* mq = m + q;
            const float* Tp = Tns + ph * 4;
            float mv = mq[0];
#pragma unroll 4
            for (int k2 = 0; k2 < 256; ++k2) {
                float nm;
                if (k2 < 255) nm = mq[(k2 + 1) * 128];
                const float4 tv = *(const float4*)&Tp[k2 * 8];
                a3[0] += tv.x * mv; a3[1] += tv.y * mv;
                a3[2] += tv.z * mv; a3[3] += tv.w * mv;
                mv = nm;
            }
            float* No = Ndst + (p0 + ph * 4) * 128 + q;
#pragma unroll
            for (int pp = 0; pp < 4; ++pp) No[pp * 128] = a3[pp];
        }
    }
}

// Partial dots: 128 blocks; final envs are in buffer 0 after 20 steps.
__global__ __launch_bounds__(256) void k_dot(float* __restrict__ ws) {
    __shared__ float se[256], sn[256];
    int bid = blockIdx.x, t = threadIdx.x;
    const float* LL = ws + OFF_LL0;
    const float* LR = ws + OFF_LR0;
    float e = 0.f;
#pragma unroll
    for (int u = 0; u < 4; ++u) {
        int i = bid * 1024 + u * 256 + t;
        e += LL[i] * LR[i];
    }
    float n = 0.f;
    if (t < 128) {
        int i = bid * 128 + t;
        n = ws[OFF_NL0 + i] * ws[OFF_NR0 + i];
    }
    se[t] = e;
    sn[t] = n;
    __syncthreads();
    for (int s = 128; s > 0; s >>= 1) {
        if (t < s) { se[t] += se[t + s]; sn[t] += sn[t + s]; }
        __syncthreads();
    }
    if (t == 0) {
        ws[OFF_PART + bid] = se[0];
        ws[OFF_PARTN + bid] = sn[0];
    }
}

__global__ __launch_bounds__(256) void k_loss(const float* __restrict__ ws,
                                              float* __restrict__ out) {
    __shared__ float se[128], sn[128];
    int t = threadIdx.x;
    if (t < 128) {
        se[t] = ws[OFF_PART + t];
        sn[t] = ws[OFF_PARTN + t];
    }
    __syncthreads();
    for (int s = 64; s > 0; s >>= 1) {
        if (t < s) { se[t] += se[t + s]; sn[t] += sn[t + s]; }
        __syncthreads();
    }
    if (t == 0) {
        float E = se[0], Nm = sn[0];
        out[0] = E;
        out[1] = Nm;
        out[2] = E / Nm;
        out[3] = fmaxf(Nm - 10000.0f, 0.0f);
    }
}

extern "C" void kernel_launch(void* const* d_in, const int* in_sizes, int n_in,
                              void* d_out, int out_size, void* d_ws, size_t ws_size,
                              hipStream_t stream) {
    const float* Min = (const float*)d_in[0];
    const float* Hin = (const float*)d_in[1];
    float* ws = (float*)d_ws;
    float* out = (float*)d_out;
    (void)in_sizes; (void)n_in; (void)out_size; (void)ws_size;

    k_prep<<<dim3(512), dim3(256), 0, stream>>>(Min, Hin, ws);
    for (int k = 0; k < HALF; ++k) {
        k_step<<<dim3(288), dim3(256), 0, stream>>>(Min, Hin, ws, k);
    }
    k_dot<<<dim3(128), dim3(256), 0, stream>>>(ws);
    k_loss<<<dim3(1), dim3(256), 0, stream>>>(ws, out);
}